// Round 3
// baseline (704.793 us; speedup 1.0000x reference)
//
#include <hip/hip_runtime.h>
#include <stdint.h>

#define N_POINTS   1048576
#define N_LEVELS   16
#define HASHMAP    524288u        // 1<<19
#define HASH_MASK  (HASHMAP - 1u)
#define PI1        2654435761u
#define PI2        805459861u

typedef float v2 __attribute__((ext_vector_type(2)));

// int(16 * (32^(1/15))^i) for i in 0..15, replicated exactly from the reference
__constant__ float c_res[16] = {16.f,20.f,25.f,32.f,40.f,50.f,64.f,80.f,
                                101.f,128.f,161.f,203.f,256.f,322.f,406.f,512.f};

__device__ __forceinline__ v2 enc_level(float x0, float x1, float x2,
                                        const float* __restrict__ tables,
                                        int level, float res) {
    float sx = x0*res, sy = x1*res, sz = x2*res;
    int ix = (int)sx, iy = (int)sy, iz = (int)sz;   // trunc == floor for x>=0
    float fx = sx - (float)ix, fy = sy - (float)iy, fz = sz - (float)iz;
    uint32_t hx0 = (uint32_t)ix,       hx1 = hx0 + 1u;
    uint32_t hy0 = (uint32_t)iy * PI1, hy1 = hy0 + PI1;
    uint32_t hz0 = (uint32_t)iz * PI2, hz1 = hz0 + PI2;
    const v2* __restrict__ tab = (const v2*)tables + (size_t)level * HASHMAP;
    uint32_t e0 = hy0 ^ hz0, e1 = hy1 ^ hz0, e2 = hy0 ^ hz1, e3 = hy1 ^ hz1;
    uint32_t i0 = (hx0 ^ e0) & HASH_MASK;
    uint32_t i1 = (hx1 ^ e0) & HASH_MASK;
    uint32_t i2 = (hx0 ^ e1) & HASH_MASK;
    uint32_t i3 = (hx1 ^ e1) & HASH_MASK;
    uint32_t i4 = (hx0 ^ e2) & HASH_MASK;
    uint32_t i5 = (hx1 ^ e2) & HASH_MASK;
    uint32_t i6 = (hx0 ^ e3) & HASH_MASK;
    uint32_t i7 = (hx1 ^ e3) & HASH_MASK;
    // all 8 gathers issued back-to-back for MLP
    v2 f0 = tab[i0], f1 = tab[i1], f2 = tab[i2], f3 = tab[i3];
    v2 f4 = tab[i4], f5 = tab[i5], f6 = tab[i6], f7 = tab[i7];
    float wx1 = fx, wx0 = 1.f - fx;
    float wy1 = fy, wy0 = 1.f - fy;
    float wz1 = fz, wz0 = 1.f - fz;
    float w00 = wy0*wz0, w10 = wy1*wz0, w01 = wy0*wz1, w11 = wy1*wz1;
    float c0 = wx0*w00, c1 = wx1*w00, c2 = wx0*w10, c3 = wx1*w10;
    float c4 = wx0*w01, c5 = wx1*w01, c6 = wx0*w11, c7 = wx1*w11;
    v2 r;
    r.x = c0*f0.x + c1*f1.x + c2*f2.x + c3*f3.x + c4*f4.x + c5*f5.x + c6*f6.x + c7*f7.x;
    r.y = c0*f0.y + c1*f1.y + c2*f2.y + c3*f3.y + c4*f4.y + c5*f5.y + c6*f6.y + c7*f7.y;
    return r;
}

// Single pass: block = 256 points, loop all 16 levels (resident blocks sweep
// levels roughly in phase -> L2 table locality; L3 holds all tables anyway),
// stash per-level v2 in LDS, then write full 128B output rows coalesced.
// LDS pitch 33 floats: both write pattern (bank = (t+2l)%32, 2-way = free)
// and read pattern are conflict-cheap. 33KB LDS -> 4 blocks/CU, 16 waves/CU.
__global__ __launch_bounds__(256) void hash_enc_all(const float* __restrict__ x,
                                                    const float* __restrict__ tables,
                                                    v2* __restrict__ out) {
    __shared__ float tile[256][33];
    int t = threadIdx.x;
    int p = (blockIdx.x << 8) | t;
    float x0 = x[3*p+0], x1 = x[3*p+1], x2 = x[3*p+2];   // read x once per point
    #pragma unroll 2
    for (int l = 0; l < N_LEVELS; ++l) {
        v2 r = enc_level(x0, x1, x2, tables, l, c_res[l]);
        tile[t][2*l]   = r.x;
        tile[t][2*l+1] = r.y;
    }
    __syncthreads();
    size_t base = ((size_t)blockIdx.x << 8) * 16;   // v2 index of block's output
    #pragma unroll
    for (int k = 0; k < 16; ++k) {
        int j  = (k << 8) | t;
        int pl = j >> 4, c2 = j & 15;
        v2 v;
        v.x = tile[pl][2*c2];
        v.y = tile[pl][2*c2+1];
        __builtin_nontemporal_store(v, out + base + j);
    }
}

extern "C" void kernel_launch(void* const* d_in, const int* in_sizes, int n_in,
                              void* d_out, int out_size, void* d_ws, size_t ws_size,
                              hipStream_t stream) {
    const float* x      = (const float*)d_in[0];
    const float* tables = (const float*)d_in[1];
    hash_enc_all<<<dim3(N_POINTS / 256), dim3(256), 0, stream>>>(x, tables, (v2*)d_out);
}

// Round 4
// 614.684 us; speedup vs baseline: 1.1466x; 1.1466x over previous
//
#include <hip/hip_runtime.h>
#include <stdint.h>

#define N_POINTS   1048576
#define N_LEVELS   16
#define HASHMAP    524288u        // 1<<19
#define HASH_MASK  (HASHMAP - 1u)
#define PI1        2654435761u
#define PI2        805459861u

typedef float v2 __attribute__((ext_vector_type(2)));
typedef float v4 __attribute__((ext_vector_type(4)));

// int(16 * (32^(1/15))^i) for i in 0..15, replicated exactly from the reference
__constant__ float c_res[16] = {16.f,20.f,25.f,32.f,40.f,50.f,64.f,80.f,
                                101.f,128.f,161.f,203.f,256.f,322.f,406.f,512.f};

// Paired-corner encode: for even ix, corners (x,·,·) and (x+1,·,·) land at hash
// indices i and i^1 -> one aligned float4 covers both. Odd-ix lanes (~50%)
// issue 4 extra exec-masked 8B gathers. 384 line-requests/wave vs 512.
__device__ __forceinline__ v2 enc_level(float x0, float x1, float x2,
                                        const float* __restrict__ tables,
                                        int level, float res) {
    float sx = x0*res, sy = x1*res, sz = x2*res;
    int ix = (int)sx, iy = (int)sy, iz = (int)sz;   // trunc == floor for x>=0
    float fx = sx - (float)ix, fy = sy - (float)iy, fz = sz - (float)iz;
    uint32_t hx0 = (uint32_t)ix;
    bool     oddx = (hx0 & 1u) != 0u;
    uint32_t hx1 = hx0 + 1u;
    uint32_t hy0 = (uint32_t)iy * PI1, hy1 = hy0 + PI1;
    uint32_t hz0 = (uint32_t)iz * PI2, hz1 = hz0 + PI2;
    const v2* __restrict__ tab  = (const v2*)tables + (size_t)level * HASHMAP;
    const v4* __restrict__ ptab = (const v4*)tab;   // 16B-aligned pair table view
    uint32_t e0 = hy0 ^ hz0, e1 = hy1 ^ hz0, e2 = hy0 ^ hz1, e3 = hy1 ^ hz1;
    uint32_t i00 = (hx0 ^ e0) & HASH_MASK, i01 = (hx1 ^ e0) & HASH_MASK;
    uint32_t i10 = (hx0 ^ e1) & HASH_MASK, i11 = (hx1 ^ e1) & HASH_MASK;
    uint32_t i20 = (hx0 ^ e2) & HASH_MASK, i21 = (hx1 ^ e2) & HASH_MASK;
    uint32_t i30 = (hx0 ^ e3) & HASH_MASK, i31 = (hx1 ^ e3) & HASH_MASK;
    // 4 aligned 16B gathers, back-to-back
    v4 q0 = ptab[i00 >> 1];
    v4 q1 = ptab[i10 >> 1];
    v4 q2 = ptab[i20 >> 1];
    v4 q3 = ptab[i30 >> 1];
    // even-x corner = entry i?0; other half of the pair = entry i?0^1 (= corner
    // x+1 iff ix even)
    v2 f0 = (i00 & 1) ? q0.zw : q0.xy;  v2 g0 = (i00 & 1) ? q0.xy : q0.zw;
    v2 f1 = (i10 & 1) ? q1.zw : q1.xy;  v2 g1 = (i10 & 1) ? q1.xy : q1.zw;
    v2 f2 = (i20 & 1) ? q2.zw : q2.xy;  v2 g2 = (i20 & 1) ? q2.xy : q2.zw;
    v2 f3 = (i30 & 1) ? q3.zw : q3.xy;  v2 g3 = (i30 & 1) ? q3.xy : q3.zw;
    if (oddx) {                         // exec-masked: only odd lanes issue
        g0 = tab[i01];
        g1 = tab[i11];
        g2 = tab[i21];
        g3 = tab[i31];
    }
    float wx1 = fx, wx0 = 1.f - fx;
    float wy1 = fy, wy0 = 1.f - fy;
    float wz1 = fz, wz0 = 1.f - fz;
    float w00 = wy0*wz0, w10 = wy1*wz0, w01 = wy0*wz1, w11 = wy1*wz1;
    float c0 = wx0*w00, c1 = wx1*w00, c2 = wx0*w10, c3 = wx1*w10;
    float c4 = wx0*w01, c5 = wx1*w01, c6 = wx0*w11, c7 = wx1*w11;
    v2 r;
    r.x = c0*f0.x + c1*g0.x + c2*f1.x + c3*g1.x + c4*f2.x + c5*g2.x + c6*f3.x + c7*g3.x;
    r.y = c0*f0.y + c1*g0.y + c2*f1.y + c3*g1.y + c4*f2.y + c5*g2.y + c6*f3.y + c7*g3.y;
    return r;
}

// Pass 1, XCD-pinned: blockIdx % 8 -> XCD (dispatch round-robin heuristic).
// XCD x sweeps level x (first 4096 of its blocks) then level 15-x -> each
// level's 4MB table is fetched into exactly one XCD L2, once; phase overlap
// within an XCD ~5% of a level. ws layout tile-contiguous: [tile][level][t].
__global__ __launch_bounds__(256) void hash_enc_xcd(const float* __restrict__ x,
                                                    const float* __restrict__ tables,
                                                    v2* __restrict__ ws) {
    int b    = blockIdx.x;
    int xcd  = b & 7;
    int seq  = b >> 3;                        // 0..8191 within this XCD
    int level = (seq & 4096) ? (15 - xcd) : xcd;
    int tile  = seq & 4095;
    int t = threadIdx.x;
    int p = (tile << 8) | t;
    float x0 = x[3*p+0], x1 = x[3*p+1], x2 = x[3*p+2];
    v2 r = enc_level(x0, x1, x2, tables, level, c_res[level]);
    __builtin_nontemporal_store(r, ws + (size_t)tile * 4096 + level * 256 + t);
}

// Pass 2: tile-contiguous ws -> (N, 32) rows. Block = 256 points: read 32KB
// contiguous (float4), LDS transpose (pitch 514 floats: conflict-free b64
// reads), write 32KB contiguous (float4). ~268MB total @ ~6TB/s -> ~45us.
#define P2PITCH 514
__global__ __launch_bounds__(256) void transpose_tile(const v4* __restrict__ ws4,
                                                      v4* __restrict__ out4) {
    __shared__ float lds[16 * P2PITCH];
    int t = threadIdx.x;
    size_t tb = (size_t)blockIdx.x * 2048;    // float4 per tile
    #pragma unroll
    for (int k = 0; k < 8; ++k) {
        v4 q = __builtin_nontemporal_load(ws4 + tb + k*256 + t);
        int m0 = 512*k + 2*t;                 // v2 index within tile
        int l  = m0 >> 8;
        int pl = m0 & 255;
        float* dst = &lds[l * P2PITCH + 2*pl];
        dst[0] = q.x; dst[1] = q.y; dst[2] = q.z; dst[3] = q.w;
    }
    __syncthreads();
    #pragma unroll
    for (int k = 0; k < 8; ++k) {
        int o  = k*256 + t;                   // out float4 index within tile
        int pp = o >> 3;                      // point in tile
        int r0 = 2 * (o & 7);                 // level-pair row
        v4 v;
        v.x = lds[ r0      * P2PITCH + 2*pp    ];
        v.y = lds[ r0      * P2PITCH + 2*pp + 1];
        v.z = lds[(r0 + 1) * P2PITCH + 2*pp    ];
        v.w = lds[(r0 + 1) * P2PITCH + 2*pp + 1];
        __builtin_nontemporal_store(v, out4 + tb + o);
    }
}

// Fallback (ws too small): fused interleaved — correct with zero workspace.
__global__ __launch_bounds__(256) void hash_enc_fused(const float* __restrict__ x,
                                                      const float* __restrict__ tables,
                                                      v2* __restrict__ out) {
    int tid = blockIdx.x * 256 + threadIdx.x;
    int level = tid & 15;
    int p = tid >> 4;
    float x0 = x[3*p+0], x1 = x[3*p+1], x2 = x[3*p+2];
    v2 r = enc_level(x0, x1, x2, tables, level, c_res[level]);
    out[tid] = r;
}

extern "C" void kernel_launch(void* const* d_in, const int* in_sizes, int n_in,
                              void* d_out, int out_size, void* d_ws, size_t ws_size,
                              hipStream_t stream) {
    const float* x      = (const float*)d_in[0];
    const float* tables = (const float*)d_in[1];
    size_t need = (size_t)N_LEVELS * N_POINTS * sizeof(v2);   // 128 MB
    if (ws_size >= need) {
        hash_enc_xcd<<<dim3(65536), dim3(256), 0, stream>>>(x, tables, (v2*)d_ws);
        transpose_tile<<<dim3(4096), dim3(256), 0, stream>>>((const v4*)d_ws, (v4*)d_out);
    } else {
        hash_enc_fused<<<dim3(65536), dim3(256), 0, stream>>>(x, tables, (v2*)d_out);
    }
}